// Round 2
// baseline (340.957 us; speedup 1.0000x reference)
//
#include <hip/hip_runtime.h>

#define DIM 4194304   // 2^22 amplitudes
// index bit b  <->  qubit q = 21-b ; layer L RY param index p = 22*L + q
// CNOT ladder (per layer) == permutation out[j] = in[j ^ (j>>1)]  (Gray encode)
// inverse: j = prefix-xor(m)

__device__ __forceinline__ int pfx(int x) {       // prefix-xor, widths <= 16
  x ^= x >> 1; x ^= x >> 2; x ^= x >> 4; x ^= x >> 8;
  return x;
}

// ---------------- K0: tiny MLP + rotation table + zero sumsq ----------------
__global__ void k0_prep(const float* __restrict__ alpha, const float* __restrict__ iawp,
                        const float* __restrict__ w1, const float* __restrict__ b1,
                        const float* __restrict__ w2, const float* __restrict__ b2,
                        const float* __restrict__ cp,
                        float* __restrict__ cs, double* __restrict__ sumsq,
                        float* __restrict__ yout) {
  int t = threadIdx.x;
  if (t < 44) {                       // cs[(L*22+b)*2 + {0:c,1:s}]
    int L = t / 22, b = t % 22;
    int q = 21 - b;
    float th = cp[L * 22 + q] * 0.5f;
    cs[2 * t]     = cosf(th);
    cs[2 * t + 1] = sinf(th);
  }
  if (t == 63) {
    *sumsq = 0.0;
    float iaw = iawp[0];
    float a[3] = {alpha[0], alpha[1], alpha[2]};
    float y[3], z[3];
    for (int i = 0; i < 3; ++i)
      y[i] = tanhf(w1[i*3]*a[0] + w1[i*3+1]*a[1] + w1[i*3+2]*a[2] + b1[i]) + a[i]*iaw;
    for (int i = 0; i < 3; ++i)
      z[i] = tanhf(w2[i*3]*y[0] + w2[i*3+1]*y[1] + w2[i*3+2]*y[2] + b2[i]) + y[i]*iaw;
    yout[0] = z[0]; yout[1] = z[1]; yout[2] = z[2];
  }
}

// ------- K1: amps = w3@y + b3 ; sumsq ; RY layer0 bits 0..13 ; write A -------
__global__ __launch_bounds__(1024) void k1_init_lo(
    const float* __restrict__ w3, const float* __restrict__ b3,
    const float* __restrict__ y3, float* __restrict__ A,
    double* __restrict__ sumsq, const float* __restrict__ cs) {
  __shared__ float lds[16384];
  const int tid = threadIdx.x;
  const int i_base = blockIdx.x << 14;          // chunk of 16384, within one half
  const float y0 = y3[0], y1 = y3[1], y2 = y3[2];
  float acc = 0.f;
  for (int r = 0; r < 4; ++r) {
    int j = (r * 1024 + tid) * 4;
    int e = i_base + j;
    const float4* wp = (const float4*)(w3 + (long)e * 3);
    float4 wa = wp[0], wb = wp[1], wc = wp[2];
    float4 bb = *(const float4*)(b3 + e);
    float4 amp;
    amp.x = wa.x*y0 + wa.y*y1 + wa.z*y2 + bb.x;
    amp.y = wa.w*y0 + wb.x*y1 + wb.y*y2 + bb.y;
    amp.z = wb.z*y0 + wb.w*y1 + wc.x*y2 + bb.z;
    amp.w = wc.y*y0 + wc.z*y1 + wc.w*y2 + bb.w;
    acc += amp.x*amp.x + amp.y*amp.y + amp.z*amp.z + amp.w*amp.w;
    *(float4*)(lds + j) = amp;
  }
  double d = (double)acc;                        // norm^2 (circuit-invariant)
  for (int o = 32; o > 0; o >>= 1) d += __shfl_down(d, o, 64);
  if ((tid & 63) == 0) atomicAdd(sumsq, d);
#pragma unroll
  for (int t = 0; t < 14; ++t) {                 // butterfly, layer 0, bit t
    float c = cs[t * 2], s = cs[t * 2 + 1];
    __syncthreads();
    for (int pi = 0; pi < 8; ++pi) {
      int i  = pi * 1024 + tid;
      int i0 = ((i >> t) << (t + 1)) | (i & ((1 << t) - 1));
      int i1 = i0 | (1 << t);
      float a0 = lds[i0], a1 = lds[i1];
      lds[i0] = c * a0 - s * a1;
      lds[i1] = s * a0 + c * a1;
    }
  }
  __syncthreads();
  for (int r = 0; r < 4; ++r) {
    int j = (r * 1024 + tid) * 4;
    *(float4*)(A + i_base + j) = *(float4*)(lds + j);
  }
}

// ------------- K2: RY layer0 bits 14..21, in-place 256hi x 64lo tiles -------------
__global__ __launch_bounds__(1024) void k2_hi(float* __restrict__ A,
                                              const float* __restrict__ cs) {
  __shared__ float lds[16384];                   // [256 h][64 l]
  const int tid = threadIdx.x;
  const int half = blockIdx.x >> 8;
  const int w = blockIdx.x & 255;                // 64-wide lo window
  float* base = A + half * DIM + w * 64;
  for (int r = 0; r < 4; ++r) {
    int h = (tid >> 4) + r * 64, l4 = (tid & 15) * 4;
    *(float4*)(lds + h * 64 + l4) = *(const float4*)(base + (long)h * 16384 + l4);
  }
#pragma unroll
  for (int tb = 0; tb < 8; ++tb) {               // bit 14+tb, layer 0
    float c = cs[(14 + tb) * 2], s = cs[(14 + tb) * 2 + 1];
    __syncthreads();
    for (int pi = 0; pi < 8; ++pi) {
      int i = pi * 1024 + tid;
      int l = i & 63, ph = i >> 6;
      int h0 = ((ph >> tb) << (tb + 1)) | (ph & ((1 << tb) - 1));
      int h1 = h0 | (1 << tb);
      float a0 = lds[h0 * 64 + l], a1 = lds[h1 * 64 + l];
      lds[h0 * 64 + l] = c * a0 - s * a1;
      lds[h1 * 64 + l] = s * a0 + c * a1;
    }
  }
  __syncthreads();
  for (int r = 0; r < 4; ++r) {
    int h = (tid >> 4) + r * 64, l4 = (tid & 15) * 4;
    *(float4*)(base + (long)h * 16384 + l4) = *(float4*)(lds + h * 64 + l4);
  }
}

// ---- K3: Gray-gather (1st CNOT ladder) + RY layer1 bits 0..13, in-place ----
// Block H reads chunk gray8(H); lds[p] holds s2[H*2^14 + l] with p = gray14(l)^flip.
__global__ __launch_bounds__(1024) void k3_perm_lo(float* __restrict__ A,
                                                   const float* __restrict__ cs) {
  __shared__ float lds[16384];
  const int tid = threadIdx.x;
  const int half = blockIdx.x >> 8;
  const int H = blockIdx.x & 255;
  const int c8 = H ^ (H >> 1);                   // gray8(H)
  const int flip = (H & 1) << 13;
  float* base = A + half * DIM + (c8 << 14);
  for (int r = 0; r < 4; ++r) {
    int j = (r * 1024 + tid) * 4;
    *(float4*)(lds + j) = *(const float4*)(base + j);
  }
#pragma unroll
  for (int t = 0; t < 14; ++t) {                 // layer 1, bit t (in s2-space)
    float c = cs[(22 + t) * 2], s = cs[(22 + t) * 2 + 1];
    __syncthreads();
    for (int pi = 0; pi < 8; ++pi) {
      int i  = pi * 1024 + tid;
      int l0 = ((i >> t) << (t + 1)) | (i & ((1 << t) - 1));
      int l1 = l0 | (1 << t);
      int p0 = (l0 ^ (l0 >> 1)) ^ flip;
      int p1 = (l1 ^ (l1 >> 1)) ^ flip;
      float a0 = lds[p0], a1 = lds[p1];
      lds[p0] = c * a0 - s * a1;
      lds[p1] = s * a0 + c * a1;
    }
  }
  __syncthreads();
  for (int r = 0; r < 4; ++r) {
    int j = (r * 1024 + tid) * 4;
    *(float4*)(base + j) = *(float4*)(lds + j);
  }
}

// K4: RY layer1 bits 14..21 + probability/N^2 + Gray-scatter (2nd ladder) -> out
// Storage after K3: s2.5[n] lives at A[gray22(n)]. Final out[pfx22(n)] = |s3[n]|^2/N^2.
__global__ __launch_bounds__(1024) void k4_hi_prob(
    const float* __restrict__ A, float* __restrict__ out,
    const float* __restrict__ cs, const double* __restrict__ sumsq) {
  __shared__ float lds[16384];                   // [2 half][256 h][32 l]
  const int tid = threadIdx.x;
  const int w = blockIdx.x;                      // 9-bit lo window (32-wide)
  const int g9w = w ^ (w >> 1);
  const int f4 = (w & 1) << 4;
  const int p9w = pfx(w);
  const int parw31 = (p9w & 1) ? 31 : 0;
  const float inv = (float)(1.0 / *sumsq);
  for (int half = 0; half < 2; ++half) {
    for (int r = 0; r < 8; ++r) {
      int h = (tid >> 5) + r * 32, l = tid & 31;
      int g5l = l ^ (l >> 1);
      int off = ((g9w << 5) | (g5l ^ f4)) ^ ((h & 1) << 13);
      lds[half * 8192 + h * 32 + l] =
          A[half * DIM + ((h ^ (h >> 1)) << 14) + off];
    }
  }
#pragma unroll
  for (int tb = 0; tb < 8; ++tb) {               // layer 1, bit 14+tb (s2-space)
    float c = cs[(22 + 14 + tb) * 2], s = cs[(22 + 14 + tb) * 2 + 1];
    __syncthreads();
    for (int pi = 0; pi < 8; ++pi) {
      int i = pi * 1024 + tid;
      int half = i >> 12, idx = i & 4095;
      int l = idx & 31, ph = idx >> 5;
      int h0 = ((ph >> tb) << (tb + 1)) | (ph & ((1 << tb) - 1));
      int h1 = h0 | (1 << tb);
      int b0 = half * 8192 + h0 * 32 + l, b1 = half * 8192 + h1 * 32 + l;
      float a0 = lds[b0], a1 = lds[b1];
      lds[b0] = c * a0 - s * a1;
      lds[b1] = s * a0 + c * a1;
    }
  }
  __syncthreads();
  for (int r = 0; r < 8; ++r) {
    int i = r * 1024 + tid;
    int l = i & 31, h = i >> 5;
    float re = lds[h * 32 + l], im = lds[8192 + h * 32 + l];
    float p = (re * re + im * im) * inv;
    int jhi = pfx(h);
    int jlo = ((pfx(w) << 5) | (pfx(l) ^ parw31)) ^ ((jhi & 1) ? 0x3FFF : 0);
    out[(jhi << 14) | jlo] = p;
  }
}

extern "C" void kernel_launch(void* const* d_in, const int* in_sizes, int n_in,
                              void* d_out, int out_size, void* d_ws, size_t ws_size,
                              hipStream_t stream) {
  const float* alpha = (const float*)d_in[0];
  const float* iaw   = (const float*)d_in[1];
  const float* w1    = (const float*)d_in[2];
  const float* b1    = (const float*)d_in[3];
  const float* w2    = (const float*)d_in[4];
  const float* b2    = (const float*)d_in[5];
  const float* w3    = (const float*)d_in[6];
  const float* b3    = (const float*)d_in[7];
  const float* cp    = (const float*)d_in[8];
  float* outp = (float*)d_out;

  double* sumsq = (double*)d_ws;                     // 8 B
  float*  cs    = (float*)d_ws + 4;                  // 88 floats
  float*  yv    = (float*)d_ws + 96;                 // 3 floats
  float*  A     = (float*)d_ws + 512;                // 2*DIM floats (32 MiB)

  k0_prep<<<1, 64, 0, stream>>>(alpha, iaw, w1, b1, w2, b2, cp, cs, sumsq, yv);
  k1_init_lo<<<512, 1024, 0, stream>>>(w3, b3, yv, A, sumsq, cs);
  k2_hi<<<512, 1024, 0, stream>>>(A, cs);
  k3_perm_lo<<<512, 1024, 0, stream>>>(A, cs);
  k4_hi_prob<<<512, 1024, 0, stream>>>(A, outp, cs, sumsq);
}

// Round 4
// 286.656 us; speedup vs baseline: 1.1894x; 1.1894x over previous
//
#include <hip/hip_runtime.h>

#define DIM 4194304   // 2^22 amplitudes
// index bit b  <->  qubit q = 21-b ; layer L RY param p -> cs[(L*22+b)*2]
// CNOT ladder (per layer) == permutation out[j] = in[j ^ (j>>1)]  (Gray encode)
// Pipeline: k1: init + L0 bits0..13 | k2: L0 bits14..21 + conjugated L1 bits14..21
//           k3: Gray-gather + L1 bits0..13 | k4: prob + Gray-scatter (streaming)

__device__ __forceinline__ int pfx(int x) {       // prefix-xor, widths <= 16
  x ^= x >> 1; x ^= x >> 2; x ^= x >> 4; x ^= x >> 8;
  return x;
}

// ---------------- K0: tiny MLP + rotation table + zero accumulators ----------------
__global__ void k0_prep(const float* __restrict__ alpha, const float* __restrict__ iawp,
                        const float* __restrict__ w1, const float* __restrict__ b1,
                        const float* __restrict__ w2, const float* __restrict__ b2,
                        const float* __restrict__ cp,
                        float* __restrict__ cs, double* __restrict__ sumsq,
                        float* __restrict__ yout, double* __restrict__ partial) {
  int t = threadIdx.x;
  partial[t] = 0.0;                  // 512 block-partials
  if (t < 44) {                      // cs[(L*22+b)*2 + {0:c,1:s}]
    int L = t / 22, b = t % 22;
    int q = 21 - b;
    float th = cp[L * 22 + q] * 0.5f;
    cs[2 * t]     = cosf(th);
    cs[2 * t + 1] = sinf(th);
  }
  if (t == 0) {
    *sumsq = 0.0;
    float iaw = iawp[0];
    float a[3] = {alpha[0], alpha[1], alpha[2]};
    float y[3], z[3];
    for (int i = 0; i < 3; ++i)
      y[i] = tanhf(w1[i*3]*a[0] + w1[i*3+1]*a[1] + w1[i*3+2]*a[2] + b1[i]) + a[i]*iaw;
    for (int i = 0; i < 3; ++i)
      z[i] = tanhf(w2[i*3]*y[0] + w2[i*3+1]*y[1] + w2[i*3+2]*y[2] + b2[i]) + y[i]*iaw;
    yout[0] = z[0]; yout[1] = z[1]; yout[2] = z[2];
  }
}

// ------- K1: amps = w3@y + b3 ; per-block sumsq partial ; L0 bits 0..13 -------
__global__ __launch_bounds__(1024) void k1_init_lo(
    const float* __restrict__ w3, const float* __restrict__ b3,
    const float* __restrict__ y3, float* __restrict__ A,
    double* __restrict__ partial, const float* __restrict__ cs) {
  __shared__ float lds[16384];
  const int tid = threadIdx.x;
  const int i_base = blockIdx.x << 14;          // chunk of 16384, within one plane
  const float y0 = y3[0], y1 = y3[1], y2 = y3[2];
  const float c0 = cs[0], s0 = cs[1], c1 = cs[2], s1 = cs[3];
  float acc = 0.f;
  for (int r = 0; r < 4; ++r) {
    int j = (r * 1024 + tid) * 4;
    int e = i_base + j;
    const float4* wp = (const float4*)(w3 + (long)e * 3);
    float4 wa = wp[0], wb = wp[1], wc = wp[2];
    float4 bb = *(const float4*)(b3 + e);
    float4 amp;
    amp.x = wa.x*y0 + wa.y*y1 + wa.z*y2 + bb.x;
    amp.y = wa.w*y0 + wb.x*y1 + wb.y*y2 + bb.y;
    amp.z = wb.z*y0 + wb.w*y1 + wc.x*y2 + bb.z;
    amp.w = wc.y*y0 + wc.z*y1 + wc.w*y2 + bb.w;
    acc += amp.x*amp.x + amp.y*amp.y + amp.z*amp.z + amp.w*amp.w;
    // bits 0 and 1 of the index live inside this float4: butterfly in registers
    { float a0 = amp.x, a1 = amp.y; amp.x = c0*a0 - s0*a1; amp.y = s0*a0 + c0*a1; }
    { float a0 = amp.z, a1 = amp.w; amp.z = c0*a0 - s0*a1; amp.w = s0*a0 + c0*a1; }
    { float a0 = amp.x, a1 = amp.z; amp.x = c1*a0 - s1*a1; amp.z = s1*a0 + c1*a1; }
    { float a0 = amp.y, a1 = amp.w; amp.y = c1*a0 - s1*a1; amp.w = s1*a0 + c1*a1; }
    *(float4*)(lds + j) = amp;
  }
  double d = (double)acc;                        // norm^2 (circuit-invariant)
  for (int o = 32; o > 0; o >>= 1) d += __shfl_down(d, o, 64);
  if ((tid & 63) == 0) atomicAdd(&partial[blockIdx.x], d);  // 512 disjoint slots
#pragma unroll
  for (int t = 2; t < 14; ++t) {                 // LDS butterfly, layer 0, bit t
    float c = cs[t * 2], s = cs[t * 2 + 1];
    __syncthreads();
    for (int pi = 0; pi < 8; ++pi) {
      int i  = pi * 1024 + tid;
      int i0 = ((i >> t) << (t + 1)) | (i & ((1 << t) - 1));
      int i1 = i0 | (1 << t);
      float a0 = lds[i0], a1 = lds[i1];
      lds[i0] = c * a0 - s * a1;
      lds[i1] = s * a0 + c * a1;
    }
  }
  __syncthreads();
  for (int r = 0; r < 4; ++r) {
    int j = (r * 1024 + tid) * 4;
    *(float4*)(A + i_base + j) = *(float4*)(lds + j);
  }
}

// ---- K2: L0 bits 14..21 + Gray-conjugated L1 bits 14..21, in-place tiles ----
// Tile: 256 rows (index bits 14..21) x 64 cols; col c = (b13<<5)|l5 maps to
// lo index (b13<<13)|(w8<<5)|l5 -- pairs bit13 so the b=14 cross-term is in-tile.
// Conjugated L1 rotation on target bit b pairs n <-> n^((1<<b)|(1<<(b-1)));
// role-0 element has parity(n>>b)==0  (proof: parity(g(j)>>b) = j_b).
__global__ __launch_bounds__(1024) void k2_hi(float* __restrict__ A,
                                              const float* __restrict__ cs,
                                              const double* __restrict__ partial,
                                              double* __restrict__ sumsq) {
  __shared__ float lds[16384];                   // [256 h][64 c]
  const int tid = threadIdx.x;
  if (blockIdx.x == 0 && tid < 512) {            // reduce 512 block partials
    double d = partial[tid];
    for (int o = 32; o > 0; o >>= 1) d += __shfl_down(d, o, 64);
    if ((tid & 63) == 0) atomicAdd(sumsq, d);    // 8 atomics total
  }
  const int plane = blockIdx.x >> 8;
  const int w8 = blockIdx.x & 255;               // lo bits 5..12
  float* base = A + plane * DIM + w8 * 32;
  for (int r = 0; r < 4; ++r) {
    int idx = r * 1024 + tid;                    // 0..4095
    int h = idx >> 4, b13 = (idx >> 3) & 1, q = idx & 7;
    *(float4*)(lds + h * 64 + b13 * 32 + q * 4) =
        *(const float4*)(base + h * 16384 + b13 * 8192 + q * 4);
  }
#pragma unroll
  for (int tb = 0; tb < 8; ++tb) {               // L0, index bit 14+tb (row bit tb)
    float c = cs[(14 + tb) * 2], s = cs[(14 + tb) * 2 + 1];
    __syncthreads();
    for (int pi = 0; pi < 8; ++pi) {
      int i = pi * 1024 + tid;
      int col = i & 63, ph = i >> 6;
      int h0 = ((ph >> tb) << (tb + 1)) | (ph & ((1 << tb) - 1));
      int h1 = h0 | (1 << tb);
      float a0 = lds[h0 * 64 + col], a1 = lds[h1 * 64 + col];
      lds[h0 * 64 + col] = c * a0 - s * a1;
      lds[h1 * 64 + col] = s * a0 + c * a1;
    }
  }
  {                                              // L1' target bit 14: mask = bit14|bit13
    float c = cs[(22 + 14) * 2], s = cs[(22 + 14) * 2 + 1];
    __syncthreads();
    for (int pi = 0; pi < 8; ++pi) {
      int i = pi * 1024 + tid;
      int col = i & 63;
      int he = (i >> 6) << 1;                    // row with bit0 = 0
      int par = __popc(he) & 1;                  // parity(n>>14) of (he,col)
      int iA = he * 64 + col, iB = (he ^ 1) * 64 + (col ^ 32);
      int i0 = par ? iB : iA, i1 = par ? iA : iB;
      float a0 = lds[i0], a1 = lds[i1];
      lds[i0] = c * a0 - s * a1;
      lds[i1] = s * a0 + c * a1;
    }
  }
#pragma unroll
  for (int b = 15; b <= 21; ++b) {               // L1' target bit b: row mask 3<<(b-15)
    float c = cs[(22 + b) * 2], s = cs[(22 + b) * 2 + 1];
    const int sh = b - 14;
    const int mR = 3 << (sh - 1);
    __syncthreads();
    for (int pi = 0; pi < 8; ++pi) {
      int i = pi * 1024 + tid;
      int col = i & 63, ph = i >> 6;
      int h0 = ((ph >> sh) << (sh + 1)) | (ph & ((1 << sh) - 1));  // bit sh = 0
      int h1 = h0 ^ mR;
      int par = __popc(h0 >> (sh + 1)) & 1;      // parity(n>>b)
      int i0 = (par ? h1 : h0) * 64 + col;
      int i1 = (par ? h0 : h1) * 64 + col;
      float a0 = lds[i0], a1 = lds[i1];
      lds[i0] = c * a0 - s * a1;
      lds[i1] = s * a0 + c * a1;
    }
  }
  __syncthreads();
  for (int r = 0; r < 4; ++r) {
    int idx = r * 1024 + tid;
    int h = idx >> 4, b13 = (idx >> 3) & 1, q = idx & 7;
    *(float4*)(base + h * 16384 + b13 * 8192 + q * 4) =
        *(float4*)(lds + h * 64 + b13 * 32 + q * 4);
  }
}

// ---- K3: Gray-gather (1st CNOT ladder) + L1 bits 0..13, in-place ----
// Block H reads chunk gray8(H); lds[p] holds s2[..] with p = gray14(l)^flip.
// After this kernel: s3[n] lives at A[gray22(n)].
__global__ __launch_bounds__(1024) void k3_perm_lo(float* __restrict__ A,
                                                   const float* __restrict__ cs) {
  __shared__ float lds[16384];
  const int tid = threadIdx.x;
  const int plane = blockIdx.x >> 8;
  const int H = blockIdx.x & 255;
  const int c8 = H ^ (H >> 1);                   // gray8(H)
  const int flip = (H & 1) << 13;
  float* base = A + plane * DIM + (c8 << 14);
  for (int r = 0; r < 4; ++r) {
    int j = (r * 1024 + tid) * 4;
    *(float4*)(lds + j) = *(const float4*)(base + j);
  }
#pragma unroll
  for (int t = 0; t < 14; ++t) {                 // layer 1, target bit t
    float c = cs[(22 + t) * 2], s = cs[(22 + t) * 2 + 1];
    __syncthreads();
    for (int pi = 0; pi < 8; ++pi) {
      int i  = pi * 1024 + tid;
      int l0 = ((i >> t) << (t + 1)) | (i & ((1 << t) - 1));
      int l1 = l0 | (1 << t);
      int p0 = (l0 ^ (l0 >> 1)) ^ flip;
      int p1 = (l1 ^ (l1 >> 1)) ^ flip;
      float a0 = lds[p0], a1 = lds[p1];
      lds[p0] = c * a0 - s * a1;
      lds[p1] = s * a0 + c * a1;
    }
  }
  __syncthreads();
  for (int r = 0; r < 4; ++r) {
    int j = (r * 1024 + tid) * 4;
    *(float4*)(base + j) = *(float4*)(lds + j);
  }
}

// ---- K4: streaming prob + 2nd Gray ladder: out[j] = |A[j ^ (j>>2)]|^2 / N^2 ----
__global__ __launch_bounds__(256) void k4_prob(const float* __restrict__ A,
                                               float* __restrict__ out,
                                               const double* __restrict__ sumsq) {
  const float inv = (float)(1.0 / *sumsq);
  int g = blockIdx.x * 256 + threadIdx.x;        // float4-group id
  int j4 = g << 2;
  int pos = j4 ^ (j4 >> 2);                      // g22(g22(j)) = j ^ (j>>2)
  int pb = pos & ~3, sh = pos & 3;
  float4 re = *(const float4*)(A + pb);
  float4 im = *(const float4*)(A + DIM + pb);
  // component permutation r -> r^sh via two swap stages (no scratch)
  if (sh & 1) {
    float t;
    t = re.x; re.x = re.y; re.y = t;  t = re.z; re.z = re.w; re.w = t;
    t = im.x; im.x = im.y; im.y = t;  t = im.z; im.z = im.w; im.w = t;
  }
  if (sh & 2) {
    float t;
    t = re.x; re.x = re.z; re.z = t;  t = re.y; re.y = re.w; re.w = t;
    t = im.x; im.x = im.z; im.z = t;  t = im.y; im.y = im.w; im.w = t;
  }
  float4 o;
  o.x = (re.x*re.x + im.x*im.x) * inv;
  o.y = (re.y*re.y + im.y*im.y) * inv;
  o.z = (re.z*re.z + im.z*im.z) * inv;
  o.w = (re.w*re.w + im.w*im.w) * inv;
  *(float4*)(out + j4) = o;
}

extern "C" void kernel_launch(void* const* d_in, const int* in_sizes, int n_in,
                              void* d_out, int out_size, void* d_ws, size_t ws_size,
                              hipStream_t stream) {
  const float* alpha = (const float*)d_in[0];
  const float* iaw   = (const float*)d_in[1];
  const float* w1    = (const float*)d_in[2];
  const float* b1    = (const float*)d_in[3];
  const float* w2    = (const float*)d_in[4];
  const float* b2    = (const float*)d_in[5];
  const float* w3    = (const float*)d_in[6];
  const float* b3    = (const float*)d_in[7];
  const float* cp    = (const float*)d_in[8];
  float* outp = (float*)d_out;

  char* w = (char*)d_ws;
  double* sumsq   = (double*)w;                  // 8 B
  float*  cs      = (float*)(w + 64);            // 88 floats
  float*  yv      = (float*)(w + 512);           // 3 floats
  double* partial = (double*)(w + 1024);         // 512 doubles
  float*  A       = (float*)(w + 8192);          // 2*DIM floats (32 MiB)

  k0_prep<<<1, 512, 0, stream>>>(alpha, iaw, w1, b1, w2, b2, cp, cs, sumsq, yv, partial);
  k1_init_lo<<<512, 1024, 0, stream>>>(w3, b3, yv, A, partial, cs);
  k2_hi<<<512, 1024, 0, stream>>>(A, cs, partial, sumsq);
  k3_perm_lo<<<512, 1024, 0, stream>>>(A, cs);
  k4_prob<<<4096, 256, 0, stream>>>(A, outp, sumsq);
}

// Round 11
// 246.418 us; speedup vs baseline: 1.3837x; 1.1633x over previous
//
#include <hip/hip_runtime.h>

#define DIM 4194304   // 2^22 amplitudes
// index bit b <-> qubit q = 21-b ; layer L RY cs[(L*22+b)*2 + {0:c,1:s}]
// CNOT ladder == out[j] = in[j^(j>>1)] (Gray). Both ladders moved to the end:
// s_final = P∘P∘L1''∘L0 |psi0>, L1'' = P^-1 L1 P: stage on bit t pairs
// n <-> n^g(1<<t) (g(1)=1, g(1<<t)=3<<(t-1)), role rho = par(n>>t).
// Uniform butterfly: x' = c*x + ss*y, ss = rho(x)? +s : -s; partner gets -ss.
// k1: init + L0 bits0..13 | k2: L0 hi + L1'' hi | k3: L1'' lo | k4: prob + P^2.

__device__ __forceinline__ void bfs(float4& X, float4& Y, float c, float ss) {
  float4 t = X;
  X.x = c*t.x + ss*Y.x; X.y = c*t.y + ss*Y.y;
  X.z = c*t.z + ss*Y.z; X.w = c*t.w + ss*Y.w;
  Y.x = c*Y.x - ss*t.x; Y.y = c*Y.y - ss*t.y;
  Y.z = c*Y.z - ss*t.z; Y.w = c*Y.w - ss*t.w;
}
// X' = c*X + ss*swap2(Y); Y' = c*Y - ss*swap2(X); swap2:(x,y,z,w)->(z,w,x,y)
__device__ __forceinline__ void bfs_sw2(float4& X, float4& Y, float c, float ss) {
  float4 t = X;
  X.x = c*t.x + ss*Y.z; X.y = c*t.y + ss*Y.w;
  X.z = c*t.z + ss*Y.x; X.w = c*t.w + ss*Y.y;
  Y.x = c*Y.x - ss*t.z; Y.y = c*Y.y - ss*t.w;
  Y.z = c*Y.z - ss*t.x; Y.w = c*Y.w - ss*t.y;
}

// radix-4 LDS pass: 2 stages (XOR float4-masks A1,A2), signed ss per stage.
#define PASS4(QB, A1, A2, C1, SS1, C2, SS2)                           \
  { __syncthreads();                                                  \
    int _q = (QB);                                                    \
    float4 F0 = L4[_q], F1 = L4[_q^(A1)], F2 = L4[_q^(A2)],           \
           F3 = L4[_q^(A1)^(A2)];                                     \
    bfs(F0, F1, (C1), (SS1)); bfs(F2, F3, (C1), (SS1));               \
    bfs(F0, F2, (C2), (SS2)); bfs(F1, F3, (C2), (SS2));               \
    L4[_q] = F0; L4[_q^(A1)] = F1; L4[_q^(A2)] = F2;                  \
    L4[_q^(A1)^(A2)] = F3; }

// ---------------- K0: tiny MLP + rotation table + zero accumulators ----------------
__global__ void k0_prep(const float* __restrict__ alpha, const float* __restrict__ iawp,
                        const float* __restrict__ w1, const float* __restrict__ b1,
                        const float* __restrict__ w2, const float* __restrict__ b2,
                        const float* __restrict__ cp,
                        float* __restrict__ cs, double* __restrict__ sumsq,
                        float* __restrict__ yout, double* __restrict__ partial) {
  int t = threadIdx.x;
  partial[t] = 0.0;
  if (t < 44) {
    int L = t / 22, b = t % 22;
    int q = 21 - b;
    float th = cp[L * 22 + q] * 0.5f;
    cs[2 * t]     = cosf(th);
    cs[2 * t + 1] = sinf(th);
  }
  if (t == 0) {
    *sumsq = 0.0;
    float iaw = iawp[0];
    float a[3] = {alpha[0], alpha[1], alpha[2]};
    float y[3], z[3];
    for (int i = 0; i < 3; ++i)
      y[i] = tanhf(w1[i*3]*a[0] + w1[i*3+1]*a[1] + w1[i*3+2]*a[2] + b1[i]) + a[i]*iaw;
    for (int i = 0; i < 3; ++i)
      z[i] = tanhf(w2[i*3]*y[0] + w2[i*3+1]*y[1] + w2[i*3+2]*y[2] + b2[i]) + y[i]*iaw;
    yout[0] = z[0]; yout[1] = z[1]; yout[2] = z[2];
  }
}

// ------- K1: amps = w3@y+b3 ; sumsq partial ; L0 bits 0..13 (t=0,1,12,13 in regs) -------
__global__ __launch_bounds__(1024, 8) void k1_init_lo(
    const float* __restrict__ w3, const float* __restrict__ b3,
    const float* __restrict__ y3, float* __restrict__ A,
    double* __restrict__ partial, const float* __restrict__ cs) {
  __shared__ float lds[16384];
  float4* L4 = (float4*)lds;
  const int tid = threadIdx.x;
  const long i_base = (long)blockIdx.x << 14;
  const float y0 = y3[0], y1 = y3[1], y2 = y3[2];
  float4 f[4];
  float acc = 0.f;
  for (int r = 0; r < 4; ++r) {
    long e = i_base + r * 4096 + tid * 4;
    const float4* wp = (const float4*)(w3 + e * 3);
    float4 wa = wp[0], wb = wp[1], wc = wp[2];
    float4 bb = *(const float4*)(b3 + e);
    float4 amp;
    amp.x = wa.x*y0 + wa.y*y1 + wa.z*y2 + bb.x;
    amp.y = wa.w*y0 + wb.x*y1 + wb.y*y2 + bb.y;
    amp.z = wb.z*y0 + wb.w*y1 + wc.x*y2 + bb.z;
    amp.w = wc.y*y0 + wc.z*y1 + wc.w*y2 + bb.w;
    acc += amp.x*amp.x + amp.y*amp.y + amp.z*amp.z + amp.w*amp.w;
    f[r] = amp;
  }
  { // t=0 (comps 0-1,2-3), t=1 (comps 0-2,1-3) in registers
    const float c0 = cs[0], s0 = cs[1], c1 = cs[2], s1 = cs[3];
    for (int r = 0; r < 4; ++r) {
      float4 a = f[r];
      float nx = c0*a.x - s0*a.y, ny = c0*a.y + s0*a.x;
      float nz = c0*a.z - s0*a.w, nw = c0*a.w + s0*a.z;
      a.x = c1*nx - s1*nz; a.z = c1*nz + s1*nx;
      a.y = c1*ny - s1*nw; a.w = c1*nw + s1*ny;
      f[r] = a;
    }
    // t=12 pairs (f0,f1),(f2,f3); t=13 pairs (f0,f2),(f1,f3)  [r = bits 12,13]
    const float cA = cs[24], sA = cs[25], cB = cs[26], sB = cs[27];
    bfs(f[0], f[1], cA, -sA); bfs(f[2], f[3], cA, -sA);
    bfs(f[0], f[2], cB, -sB); bfs(f[1], f[3], cB, -sB);
  }
  for (int r = 0; r < 4; ++r) L4[r * 1024 + tid] = f[r];
  double d = (double)acc;                       // norm^2 (circuit-invariant)
  for (int o = 32; o > 0; o >>= 1) d += __shfl_down(d, o, 64);
  if ((tid & 63) == 0) atomicAdd(&partial[blockIdx.x], d);
  // LDS radix-4 passes: t=2..11 (plain: ss = -s)
  PASS4(tid * 4,                      1,     2,     cs[4],  -cs[5],  cs[6],  -cs[7]);
  PASS4((tid&3)   | ((tid>>2) << 4),  4,     8,     cs[8],  -cs[9],  cs[10], -cs[11]);
  PASS4((tid&15)  | ((tid>>4) << 6),  0x10,  0x20,  cs[12], -cs[13], cs[14], -cs[15]);
  PASS4((tid&63)  | ((tid>>6) << 8),  0x40,  0x80,  cs[16], -cs[17], cs[18], -cs[19]);
  __syncthreads();
  { // final pass t=10,11 -> write straight to global (coalesced)
    int q = (tid & 255) | ((tid >> 8) << 10);
    float4 F0 = L4[q], F1 = L4[q^0x100], F2 = L4[q^0x200], F3 = L4[q^0x300];
    bfs(F0, F1, cs[20], -cs[21]); bfs(F2, F3, cs[20], -cs[21]);
    bfs(F0, F2, cs[22], -cs[23]); bfs(F1, F3, cs[22], -cs[23]);
    float4* A4 = (float4*)A + (i_base >> 2);
    A4[q] = F0; A4[q^0x100] = F1; A4[q^0x200] = F2; A4[q^0x300] = F3;
  }
}

// ---- K2: L0 bits14..21 + L1'' bits14..21, in-place [256h x 64c] tiles ----
// LDS addr a: comps = n0,n1; a0..2 = n2..4; a3 = n13; a4..11 = n14..21 (=h).
__global__ __launch_bounds__(1024, 8) void k2_hi(float* __restrict__ A,
                                                 const float* __restrict__ cs,
                                                 const double* __restrict__ partial,
                                                 double* __restrict__ sumsq) {
  __shared__ float lds[16384];
  float4* L4 = (float4*)lds;
  const int tid = threadIdx.x;
  if (blockIdx.x == 0 && tid < 512) {           // reduce 512 block partials
    double d = partial[tid];
    for (int o = 32; o > 0; o >>= 1) d += __shfl_down(d, o, 64);
    if ((tid & 63) == 0) atomicAdd(sumsq, d);
  }
  const int plane = blockIdx.x >> 8;
  const int w8 = blockIdx.x & 255;              // n bits 5..12
  float4* B4 = (float4*)(A + plane * DIM + w8 * 32);
  for (int r = 0; r < 4; ++r) {
    int idx = r * 1024 + tid;
    int h = idx >> 4, b13 = (idx >> 3) & 1, q = idx & 7;
    L4[(h << 4) | (b13 << 3) | q] = B4[h * 4096 + b13 * 2048 + q];
  }
  // L0 hi: plain row-bit stages (addr mask = 1<<(tb+4))
  PASS4((tid&15)  | ((tid>>4) << 6),  0x10,  0x20,  cs[28], -cs[29], cs[30], -cs[31]); // b14,15
  PASS4((tid&63)  | ((tid>>6) << 8),  0x40,  0x80,  cs[32], -cs[33], cs[34], -cs[35]); // b16,17
  PASS4((tid&255) | ((tid>>8) << 10), 0x100, 0x200, cs[36], -cs[37], cs[38], -cs[39]); // b18,19
  PASS4(tid,                          0x400, 0x800, cs[40], -cs[41], cs[42], -cs[43]); // b20,21
  // L1'' hi: stage b pairs n^((1<<b)|(1<<(b-1))), rho = par(n>>b)
  { int hi = tid >> 1;
    int q = (hi & 7) | ((tid & 1) << 3) | ((hi >> 3) << 6);
    float s1 = (__popc(q >> 4) & 1) ? cs[73] : -cs[73];   // b14
    float s2 = (__popc(q >> 5) & 1) ? cs[75] : -cs[75];   // b15
    PASS4(q, 0x18, 0x30, cs[72], s1, cs[74], s2);
  }
  { int hi = tid >> 1;
    int q = (hi & 0x1F) | ((tid & 1) << 5) | ((hi >> 5) << 8);
    float s1 = (__popc(q >> 6) & 1) ? cs[77] : -cs[77];   // b16
    float s2 = (__popc(q >> 7) & 1) ? cs[79] : -cs[79];   // b17
    PASS4(q, 0x60, 0xC0, cs[76], s1, cs[78], s2);
  }
  { int hi = tid >> 1;
    int q = (hi & 0x7F) | ((tid & 1) << 7) | ((hi >> 7) << 10);
    float s1 = (__popc(q >> 8) & 1) ? cs[81] : -cs[81];   // b18
    float s2 = (__popc(q >> 9) & 1) ? cs[83] : -cs[83];   // b19
    PASS4(q, 0x180, 0x300, cs[80], s1, cs[82], s2);
  }
  { int hi = tid >> 1;
    int q = (hi & 0x1FF) | ((tid & 1) << 9);
    float s1 = (__popc(q >> 10) & 1) ? cs[85] : -cs[85];  // b20
    float s2 = (__popc(q >> 11) & 1) ? cs[87] : -cs[87];  // b21
    PASS4(q, 0x600, 0xC00, cs[84], s1, cs[86], s2);
  }
  __syncthreads();
  for (int r = 0; r < 4; ++r) {
    int idx = r * 1024 + tid;
    int h = idx >> 4, b13 = (idx >> 3) & 1, q = idx & 7;
    B4[h * 4096 + b13 * 2048 + q] = L4[(h << 4) | (b13 << 3) | q];
  }
}

// ---- K3: L1'' bits 0..13 on contiguous chunks (no Gray addressing) ----
// stage t pairs n^g(1<<t); rho = par(n>>t) = par(lo>>t) ^ par(c8).
__global__ __launch_bounds__(1024, 8) void k3_conj_lo(float* __restrict__ A,
                                                      const float* __restrict__ cs) {
  __shared__ float lds[16384];
  float4* L4 = (float4*)lds;
  const int tid = threadIdx.x;
  const int plane = blockIdx.x >> 8;
  const int c8 = blockIdx.x & 255;
  const int Pc = __popc(c8) & 1;
  float4* A4 = (float4*)A + (((long)plane * DIM + ((long)c8 << 14)) >> 2);
  float4 f[4];
  for (int r = 0; r < 4; ++r) f[r] = A4[r * 1024 + tid];
  const int T = (__popc(tid) & 1) ^ Pc;         // par(tid)^Pc
  { // t=0 (mask 1), t=1 (mask 3): comps; sign depends on par(r)^T
    const float c0 = cs[44], s0 = cs[45], c1v = cs[46], s1v = cs[47];
    for (int r = 0; r < 4; ++r) {
      int rho = ((r ^ (r >> 1)) & 1) ^ T;       // par(r)^T
      float ss0 = rho ? s0 : -s0;
      float ss1 = rho ? s1v : -s1v;
      float4 a = f[r];
      // t=0: pairs (x,y) sign ss0 on x; (z,w) sign -ss0 on z
      float nx = c0*a.x + ss0*a.y, ny = c0*a.y - ss0*a.x;
      float nz = c0*a.z - ss0*a.w, nw = c0*a.w + ss0*a.z;
      // t=1 (mask 3): pairs (x,w),(y,z), sign ss1 on x and y
      a.x = c1v*nx + ss1*nw; a.w = c1v*nw - ss1*nx;
      a.y = c1v*ny + ss1*nz; a.z = c1v*nz - ss1*ny;
      f[r] = a;
    }
    // t=13 (mask 0x3000): pairs (f0,f3),(f1,f2); rho(bit13=0) = Pc
    const float cD = cs[70], sD = cs[71];
    float ssD = Pc ? sD : -sD;
    bfs(f[0], f[3], cD, ssD); bfs(f[1], f[2], cD, ssD);
  }
  for (int r = 0; r < 4; ++r) L4[r * 1024 + tid] = f[r];
  __syncthreads();
  { // t=2 (addr mask 1 + comp^2), t=3 (addr mask 3)
    int q = tid * 4;
    float4 F0 = L4[q], F1 = L4[q^1], F2 = L4[q^2], F3 = L4[q^3];
    const float c2v = cs[48], s2v = cs[49], c3v = cs[50], s3v = cs[51];
    float ss2 = T ? s2v : -s2v;                 // rho(F0) = par(q)^Pc = T
    bfs_sw2(F0, F1, c2v, ss2); bfs_sw2(F2, F3, c2v, -ss2);
    float ss3 = T ? s3v : -s3v;                 // rho = par(q>>1)^Pc = T
    bfs(F0, F3, c3v, ss3); bfs(F1, F2, c3v, ss3);
    L4[q] = F0; L4[q^1] = F1; L4[q^2] = F2; L4[q^3] = F3;
  }
  // PB passes (conj masks 3<<(t-1) in n -> addr masks; 3-bit orbit bases)
  { int hi = tid >> 1;
    int q = (hi & 1) | ((tid & 1) << 3) | ((hi >> 1) << 4);
    float s1 = ((__popc(q >> 2) & 1) ^ Pc) ? cs[53] : -cs[53];  // t=4
    float s2 = ((__popc(q >> 3) & 1) ^ Pc) ? cs[55] : -cs[55];  // t=5
    PASS4(q, 6, 0xC, cs[52], s1, cs[54], s2);
  }
  { int hi = tid >> 1;
    int q = (hi & 7) | ((tid & 1) << 3) | ((hi >> 3) << 6);
    float s1 = ((__popc(q >> 4) & 1) ^ Pc) ? cs[57] : -cs[57];  // t=6
    float s2 = ((__popc(q >> 5) & 1) ^ Pc) ? cs[59] : -cs[59];  // t=7
    PASS4(q, 0x18, 0x30, cs[56], s1, cs[58], s2);
  }
  { int hi = tid >> 1;
    int q = (hi & 0x1F) | ((tid & 1) << 5) | ((hi >> 5) << 8);
    float s1 = ((__popc(q >> 6) & 1) ^ Pc) ? cs[61] : -cs[61];  // t=8
    float s2 = ((__popc(q >> 7) & 1) ^ Pc) ? cs[63] : -cs[63];  // t=9
    PASS4(q, 0x60, 0xC0, cs[60], s1, cs[62], s2);
  }
  { int hi = tid >> 1;
    int q = (hi & 0x7F) | ((tid & 1) << 7) | ((hi >> 7) << 10);
    float s1 = ((__popc(q >> 8) & 1) ^ Pc) ? cs[65] : -cs[65];  // t=10
    float s2 = ((__popc(q >> 9) & 1) ^ Pc) ? cs[67] : -cs[67];  // t=11
    PASS4(q, 0x180, 0x300, cs[64], s1, cs[66], s2);
  }
  __syncthreads();
  { // t=12 (addr mask 0x600), radix-2 x2, store to global
    const float cE = cs[68], sE = cs[69];
    float ssE = Pc ? sE : -sE;                  // rho(bits10,11=0) = Pc
    int qa = tid, qb = tid | 0x800;
    float4 F0 = L4[qa], F1 = L4[qa^0x600], F2 = L4[qb], F3 = L4[qb^0x600];
    bfs(F0, F1, cE, ssE);                       // par(qa>>10) = 0
    bfs(F2, F3, cE, -ssE);                      // par(qb>>10) = 1
    A4[qa] = F0; A4[qa^0x600] = F1; A4[qb] = F2; A4[qb^0x600] = F3;
  }
}

// ---- K4: streaming prob + P^2: out[j] = |A[j ^ (j>>2)]|^2 / N^2 ----
__global__ __launch_bounds__(256) void k4_prob(const float* __restrict__ A,
                                               float* __restrict__ out,
                                               const double* __restrict__ sumsq) {
  const float inv = (float)(1.0 / *sumsq);
  int g = blockIdx.x * 256 + threadIdx.x;
  int j4 = g << 2;
  int pos = j4 ^ (j4 >> 2);
  int pb = pos & ~3, sh = pos & 3;
  float4 re = *(const float4*)(A + pb);
  float4 im = *(const float4*)(A + DIM + pb);
  if (sh & 1) {
    float t;
    t = re.x; re.x = re.y; re.y = t;  t = re.z; re.z = re.w; re.w = t;
    t = im.x; im.x = im.y; im.y = t;  t = im.z; im.z = im.w; im.w = t;
  }
  if (sh & 2) {
    float t;
    t = re.x; re.x = re.z; re.z = t;  t = re.y; re.y = re.w; re.w = t;
    t = im.x; im.x = im.z; im.z = t;  t = im.y; im.y = im.w; im.w = t;
  }
  float4 o;
  o.x = (re.x*re.x + im.x*im.x) * inv;
  o.y = (re.y*re.y + im.y*im.y) * inv;
  o.z = (re.z*re.z + im.z*im.z) * inv;
  o.w = (re.w*re.w + im.w*im.w) * inv;
  *(float4*)(out + j4) = o;
}

extern "C" void kernel_launch(void* const* d_in, const int* in_sizes, int n_in,
                              void* d_out, int out_size, void* d_ws, size_t ws_size,
                              hipStream_t stream) {
  const float* alpha = (const float*)d_in[0];
  const float* iaw   = (const float*)d_in[1];
  const float* w1    = (const float*)d_in[2];
  const float* b1    = (const float*)d_in[3];
  const float* w2    = (const float*)d_in[4];
  const float* b2    = (const float*)d_in[5];
  const float* w3    = (const float*)d_in[6];
  const float* b3    = (const float*)d_in[7];
  const float* cp    = (const float*)d_in[8];
  float* outp = (float*)d_out;

  char* w = (char*)d_ws;
  double* sumsq   = (double*)w;                  // 8 B
  float*  cs      = (float*)(w + 64);            // 88 floats
  float*  yv      = (float*)(w + 512);           // 3 floats
  double* partial = (double*)(w + 1024);         // 512 doubles
  float*  A       = (float*)(w + 8192);          // 2*DIM floats (32 MiB)

  k0_prep<<<1, 512, 0, stream>>>(alpha, iaw, w1, b1, w2, b2, cp, cs, sumsq, yv, partial);
  k1_init_lo<<<512, 1024, 0, stream>>>(w3, b3, yv, A, partial, cs);
  k2_hi<<<512, 1024, 0, stream>>>(A, cs, partial, sumsq);
  k3_conj_lo<<<512, 1024, 0, stream>>>(A, cs);
  k4_prob<<<4096, 256, 0, stream>>>(A, outp, sumsq);
}